// Round 5
// baseline (445.804 us; speedup 1.0000x reference)
//
#include <hip/hip_runtime.h>
#include <hip/hip_bf16.h>

typedef __hip_bfloat16 bf16;
typedef __attribute__((ext_vector_type(8))) short short8;
typedef __attribute__((ext_vector_type(4))) float f32x4;
typedef __attribute__((ext_vector_type(4))) unsigned short us4;

#define EMB 1024
#define HEADS 16
#define HD 64
#define BATCH 2
#define SEQ 2048
#define ROWS (BATCH * SEQ) /* 4096 */

// Q pre-scale: attention 1/sqrt(64) folded with log2(e) so softmax runs in
// exp2 domain (v_exp_f32 is natively 2^x).
#define QSCALE (0.125f * 1.44269504088896340736f)

__device__ __forceinline__ void gload_lds16(const void* g, void* l) {
  __builtin_amdgcn_global_load_lds(
      (const __attribute__((address_space(1))) void*)g,
      (__attribute__((address_space(3))) void*)l, 16, 0, 0);
}

__device__ __forceinline__ unsigned short f2bf(float x) {
  bf16 h = __float2bfloat16(x);
  return __builtin_bit_cast(unsigned short, h);
}

// fused f32 -> bf16 (RN) for x, qkv_w, proj_w (3 segments, one launch).
__global__ __launch_bounds__(256) void cvt3_kernel(
    const float* __restrict__ a, const float* __restrict__ b,
    const float* __restrict__ cc, unsigned short* __restrict__ oa,
    unsigned short* __restrict__ ob, unsigned short* __restrict__ oc, int na4,
    int nb4, int nc4) {
  int i = blockIdx.x * 256 + threadIdx.x;
  const float* src;
  unsigned short* dst;
  int j = i;
  if (j < na4) {
    src = a;
    dst = oa;
  } else if ((j -= na4) < nb4) {
    src = b;
    dst = ob;
  } else if ((j -= nb4) < nc4) {
    src = cc;
    dst = oc;
  } else {
    return;
  }
  const float4 v = ((const float4*)src)[j];
  us4 o;
  o[0] = f2bf(v.x);
  o[1] = f2bf(v.y);
  o[2] = f2bf(v.z);
  o[3] = f2bf(v.w);
  ((us4*)dst)[j] = o;
}

// C[M,*] = A[M,K] @ B[N,K]^T + bias (f32), bf16 in, f32 accum.
// MODE 0: scatter Q [bh,tok,hd] (xQSCALE), K [bh,tok,hd], V TRANSPOSED [bh,hd,tok].
// MODE 1: f32 out: outF[row*N+col] = acc + bias.
template <int MODE>
__global__ __launch_bounds__(256) void gemm_bt(
    const bf16* __restrict__ A, const bf16* __restrict__ B,
    const float* __restrict__ bias,
    unsigned short* __restrict__ out0, unsigned short* __restrict__ out1,
    unsigned short* __restrict__ out2, float* __restrict__ outF, int N, int K) {
  __shared__ unsigned short As[128 * 64];
  __shared__ unsigned short Bs[128 * 64];
  const int lane = threadIdx.x & 63;
  const int wv = threadIdx.x >> 6;
  const int m0 = blockIdx.y * 128;
  const int n0 = blockIdx.x * 128;
  const int wr = wv >> 1, wc = wv & 1;

  f32x4 acc[4][4] = {};

  const int srow = lane >> 3;       // 0..7
  const int scol = (lane & 7) * 8;  // element col within K-step
  const bf16* Ag = A + (size_t)(m0 + wv * 32 + srow) * K + scol;
  const bf16* Bg = B + (size_t)(n0 + wv * 32 + srow) * K + scol;

  for (int k0 = 0; k0 < K; k0 += 64) {
#pragma unroll
    for (int i = 0; i < 4; ++i) {
      gload_lds16(Ag + (size_t)(i * 8) * K + k0, As + (wv * 32 + i * 8) * 64);
      gload_lds16(Bg + (size_t)(i * 8) * K + k0, Bs + (wv * 32 + i * 8) * 64);
    }
    __syncthreads();
#pragma unroll
    for (int kk = 0; kk < 2; ++kk) {
      short8 a[4], b[4];
#pragma unroll
      for (int i = 0; i < 4; ++i)
        a[i] = *(const short8*)(As + (wr * 64 + i * 16 + (lane & 15)) * 64 +
                                kk * 32 + (lane >> 4) * 8);
#pragma unroll
      for (int i = 0; i < 4; ++i)
        b[i] = *(const short8*)(Bs + (wc * 64 + i * 16 + (lane & 15)) * 64 +
                                kk * 32 + (lane >> 4) * 8);
#pragma unroll
      for (int mi = 0; mi < 4; ++mi)
#pragma unroll
        for (int ni = 0; ni < 4; ++ni)
          acc[mi][ni] = __builtin_amdgcn_mfma_f32_16x16x32_bf16(
              a[mi], b[ni], acc[mi][ni], 0, 0, 0);
    }
    __syncthreads();
  }

#pragma unroll
  for (int mi = 0; mi < 4; ++mi) {
#pragma unroll
    for (int ni = 0; ni < 4; ++ni) {
      const int col = n0 + wc * 64 + ni * 16 + (lane & 15);
      const float bv = bias[col];
#pragma unroll
      for (int r = 0; r < 4; ++r) {
        const int row = m0 + wr * 64 + mi * 16 + (lane >> 4) * 4 + r;
        float v = acc[mi][ni][r] + bv;
        if (MODE == 0) {
          const int part = col >> 10;
          const int h = (col & 1023) >> 6;
          const int hd = col & 63;
          const int bb = row >> 11;
          const int tok = row & 2047;
          const size_t bh = (size_t)(bb * HEADS + h);
          if (part == 0) {
            out0[(bh * SEQ + tok) * HD + hd] = f2bf(v * QSCALE);
          } else if (part == 1) {
            out1[(bh * SEQ + tok) * HD + hd] = f2bf(v);
          } else {  // V: store transposed [bh][hd][tok]
            out2[(bh * HD + hd) * SEQ + tok] = f2bf(v);
          }
        } else {
          outF[(size_t)row * N + col] = v;
        }
      }
    }
  }
}

// KV-split flash attention. grid (B*H, SEQ/128), 512 thr = 8 waves.
// Waves 0-3: q-subtiles x kv [0,1024). Waves 4-7: same q x kv [1024,2048).
// Flash-merge of the two halves at the end through LDS (P-buffer reused).
// K [bh,kv,hd] / Vt [bh,hd,kv] fragments read straight from global (L2-hot).
__global__ __launch_bounds__(512, 4) void attn_kernel(
    const bf16* __restrict__ Q, const bf16* __restrict__ Kx,
    const bf16* __restrict__ Vt, unsigned short* __restrict__ O) {
  __shared__ unsigned short Ps[8][32 * 64];  // per-wave P; reused as f32 o-staging
  __shared__ float Ml[4][32][2];             // partner (m,l) per q-row
  const int lane = threadIdx.x & 63;
  const int wv = threadIdx.x >> 6;  // 0..7
  const int qw = wv & 3;            // q sub-block (32 rows)
  const int half = wv >> 2;         // kv half
  const int c = lane & 15;
  const int q4 = lane >> 4;
  const int bh = blockIdx.x;
  const int b = bh >> 4;
  const int h = bh & 15;
  const int q0 = blockIdx.y * 128 + qw * 32;
  const size_t base = (size_t)bh * SEQ * HD;
  unsigned short* Pw = Ps[wv];

  // Q fragments (pre-scaled by QSCALE in the QKV epilogue)
  short8 qf[2][2];
#pragma unroll
  for (int mi = 0; mi < 2; ++mi)
#pragma unroll
    for (int kk = 0; kk < 2; ++kk)
      qf[mi][kk] = *(const short8*)(Q + base + (size_t)(q0 + mi * 16 + c) * HD +
                                    kk * 32 + q4 * 8);

  f32x4 o[2][4] = {};
  float mrow[2][4], lrow[2][4];
#pragma unroll
  for (int mi = 0; mi < 2; ++mi)
#pragma unroll
    for (int r = 0; r < 4; ++r) {
      mrow[mi][r] = -3.0e38f;
      lrow[mi][r] = 0.f;
    }

  const int kvbase = half * (SEQ / 2);
  for (int t = 0; t < (SEQ / 2) / 64; ++t) {
    const int kv0 = kvbase + t * 64;
    short8 kf[2][4], vf[2][4];
#pragma unroll
    for (int kk = 0; kk < 2; ++kk)
#pragma unroll
      for (int n = 0; n < 4; ++n)
        kf[kk][n] = *(const short8*)(Kx + base +
                                     (size_t)(kv0 + n * 16 + c) * HD +
                                     kk * 32 + q4 * 8);
#pragma unroll
    for (int kk = 0; kk < 2; ++kk)  // V issued early; consumed after softmax
#pragma unroll
      for (int n = 0; n < 4; ++n)
        vf[kk][n] = *(const short8*)(Vt + base + (size_t)(n * 16 + c) * SEQ +
                                     kv0 + kk * 32 + q4 * 8);

    // S = Q K^T (log2-domain scores)
    f32x4 s[2][4] = {};
    __builtin_amdgcn_s_setprio(1);
#pragma unroll
    for (int kk = 0; kk < 2; ++kk)
#pragma unroll
      for (int n = 0; n < 4; ++n)
#pragma unroll
        for (int mi = 0; mi < 2; ++mi)
          s[mi][n] = __builtin_amdgcn_mfma_f32_16x16x32_bf16(
              qf[mi][kk], kf[kk][n], s[mi][n], 0, 0, 0);
    __builtin_amdgcn_s_setprio(0);

#pragma unroll
    for (int mi = 0; mi < 2; ++mi) {
      float mx[4];
#pragma unroll
      for (int r = 0; r < 4; ++r) {
        float v = fmaxf(fmaxf(s[mi][0][r], s[mi][1][r]),
                        fmaxf(s[mi][2][r], s[mi][3][r]));
        v = fmaxf(v, __shfl_xor(v, 1));
        v = fmaxf(v, __shfl_xor(v, 2));
        v = fmaxf(v, __shfl_xor(v, 4));
        v = fmaxf(v, __shfl_xor(v, 8));
        mx[r] = v;
      }
      bool lc = true;
#pragma unroll
      for (int r = 0; r < 4; ++r) lc = lc && (mx[r] <= mrow[mi][r] + 8.0f);
      if (!__all(lc)) {  // T13 defer-max (P <= 2^8)
#pragma unroll
        for (int r = 0; r < 4; ++r) {
          const float mnew = fmaxf(mrow[mi][r], mx[r]);
          const float corr = exp2f(mrow[mi][r] - mnew);
          mrow[mi][r] = mnew;
          lrow[mi][r] *= corr;
#pragma unroll
          for (int n = 0; n < 4; ++n) o[mi][n][r] *= corr;
        }
      }
#pragma unroll
      for (int r = 0; r < 4; ++r) {
        const int row = mi * 16 + q4 * 4 + r;
        float rs = 0.f;
#pragma unroll
        for (int n = 0; n < 4; ++n) {
          const float p = exp2f(s[mi][n][r] - mrow[mi][r]);
          rs += p;
          const int col = n * 16 + c;
          Pw[row * 64 + (((col >> 3) ^ (row & 7)) << 3) + (col & 7)] = f2bf(p);
        }
        rs += __shfl_xor(rs, 1);
        rs += __shfl_xor(rs, 2);
        rs += __shfl_xor(rs, 4);
        rs += __shfl_xor(rs, 8);
        lrow[mi][r] += rs;
      }
    }

    // P back as A-fragments (swizzled read), then O += P V
    short8 pa[2][2];
#pragma unroll
    for (int mi = 0; mi < 2; ++mi)
#pragma unroll
      for (int kk = 0; kk < 2; ++kk) {
        const int row = mi * 16 + c;
        const int slot = (kk * 4 + q4) ^ (row & 7);
        pa[mi][kk] = *(const short8*)(Pw + row * 64 + slot * 8);
      }
    __builtin_amdgcn_s_setprio(1);
#pragma unroll
    for (int kk = 0; kk < 2; ++kk)
#pragma unroll
      for (int n = 0; n < 4; ++n)
#pragma unroll
        for (int mi = 0; mi < 2; ++mi)
          o[mi][n] = __builtin_amdgcn_mfma_f32_16x16x32_bf16(
              pa[mi][kk], vf[kk][n], o[mi][n], 0, 0, 0);
    __builtin_amdgcn_s_setprio(0);
  }

  // ---- flash-merge of kv halves (waves 4-7 stage into Ps as f32) ----
  __syncthreads();
  float* Om = (float*)&Ps[0][0];  // 8192 floats = 32 KB; slot qw*2048
  if (half == 1) {
#pragma unroll
    for (int mi = 0; mi < 2; ++mi)
#pragma unroll
      for (int n = 0; n < 4; ++n)
#pragma unroll
        for (int r = 0; r < 4; ++r)
          Om[qw * 2048 + (mi * 16 + q4 * 4 + r) * 64 + n * 16 + c] =
              o[mi][n][r];
    if (c == 0) {
#pragma unroll
      for (int mi = 0; mi < 2; ++mi)
#pragma unroll
        for (int r = 0; r < 4; ++r) {
          Ml[qw][mi * 16 + q4 * 4 + r][0] = mrow[mi][r];
          Ml[qw][mi * 16 + q4 * 4 + r][1] = lrow[mi][r];
        }
    }
  }
  __syncthreads();
  if (half == 0) {
#pragma unroll
    for (int mi = 0; mi < 2; ++mi)
#pragma unroll
      for (int r = 0; r < 4; ++r) {
        const int row = mi * 16 + q4 * 4 + r;
        const float mb = Ml[qw][row][0];
        const float lb = Ml[qw][row][1];
        const float m = fmaxf(mrow[mi][r], mb);
        const float ca = exp2f(mrow[mi][r] - m);
        const float cb = exp2f(mb - m);
        const float inv = 1.0f / (lrow[mi][r] * ca + lb * cb);
#pragma unroll
        for (int n = 0; n < 4; ++n) {
          const float ob = Om[qw * 2048 + row * 64 + n * 16 + c];
          const float res = (o[mi][n][r] * ca + ob * cb) * inv;
          O[((size_t)b * SEQ + q0 + row) * EMB + h * HD + n * 16 + c] =
              f2bf(res);
        }
      }
  }
}

extern "C" void kernel_launch(void* const* d_in, const int* in_sizes, int n_in,
                              void* d_out, int out_size, void* d_ws,
                              size_t ws_size, hipStream_t stream) {
  const float* x = (const float*)d_in[0];
  const float* qkv_w = (const float*)d_in[1];
  const float* qkv_b = (const float*)d_in[2];
  const float* proj_w = (const float*)d_in[3];
  const float* proj_b = (const float*)d_in[4];

  const size_t n_x = (size_t)ROWS * EMB;
  const size_t n_qkvw = (size_t)3 * EMB * EMB;
  const size_t n_projw = (size_t)EMB * EMB;
  const size_t elems = (size_t)BATCH * HEADS * SEQ * HD;

  unsigned short* xb = (unsigned short*)d_ws;
  unsigned short* wqkv = xb + n_x;
  unsigned short* wproj = wqkv + n_qkvw;
  unsigned short* Qw = wproj + n_projw;
  unsigned short* Kw = Qw + elems;
  unsigned short* Vw = Kw + elems;  // transposed [bh][hd][tok]
  unsigned short* Ow = Vw + elems;  // [B, SEQ, EMB]

  // 0) f32 -> bf16 conversions (single fused launch)
  const int na4 = (int)(n_x / 4), nb4 = (int)(n_qkvw / 4),
            nc4 = (int)(n_projw / 4);
  cvt3_kernel<<<(na4 + nb4 + nc4 + 255) / 256, 256, 0, stream>>>(
      x, qkv_w, proj_w, xb, wqkv, wproj, na4, nb4, nc4);

  // 1) QKV projection -> Q/K scatter + V transposed scatter
  dim3 g1(3 * EMB / 128, ROWS / 128);  // 24 x 32
  gemm_bt<0><<<g1, 256, 0, stream>>>((const bf16*)xb, (const bf16*)wqkv, qkv_b,
                                     Qw, Kw, Vw, nullptr, 3 * EMB, EMB);

  // 2) KV-split flash attention -> Ow [B, SEQ, EMB]
  dim3 g2(BATCH * HEADS, SEQ / 128);  // 32 x 16, 512 thr
  attn_kernel<<<g2, 512, 0, stream>>>((const bf16*)Qw, (const bf16*)Kw,
                                      (const bf16*)Vw, Ow);

  // 3) output projection + bias -> d_out (f32)
  dim3 g3(EMB / 128, ROWS / 128);  // 8 x 32
  gemm_bt<1><<<g3, 256, 0, stream>>>((const bf16*)Ow, (const bf16*)wproj,
                                     proj_b, nullptr, nullptr, nullptr,
                                     (float*)d_out, EMB, EMB);
}

// Round 6
// 226.956 us; speedup vs baseline: 1.9643x; 1.9643x over previous
//
#include <hip/hip_runtime.h>
#include <hip/hip_bf16.h>

typedef __hip_bfloat16 bf16;
typedef __attribute__((ext_vector_type(8))) short short8;
typedef __attribute__((ext_vector_type(4))) float f32x4;
typedef __attribute__((ext_vector_type(4))) unsigned short us4;

#define EMB 1024
#define HEADS 16
#define HD 64
#define BATCH 2
#define SEQ 2048
#define ROWS (BATCH * SEQ) /* 4096 */

// Q pre-scale: attention 1/sqrt(64) folded with log2(e) so softmax runs in
// exp2 domain (v_exp_f32 is natively 2^x).
#define QSCALE (0.125f * 1.44269504088896340736f)

__device__ __forceinline__ void gload_lds16(const void* g, void* l) {
  __builtin_amdgcn_global_load_lds(
      (const __attribute__((address_space(1))) void*)g,
      (__attribute__((address_space(3))) void*)l, 16, 0, 0);
}

__device__ __forceinline__ unsigned short f2bf(float x) {
  bf16 h = __float2bfloat16(x);
  return __builtin_bit_cast(unsigned short, h);
}

// fused f32 -> bf16 (RN) for x, qkv_w, proj_w (3 segments, one launch).
__global__ __launch_bounds__(256) void cvt3_kernel(
    const float* __restrict__ a, const float* __restrict__ b,
    const float* __restrict__ cc, unsigned short* __restrict__ oa,
    unsigned short* __restrict__ ob, unsigned short* __restrict__ oc, int na4,
    int nb4, int nc4) {
  int i = blockIdx.x * 256 + threadIdx.x;
  const float* src;
  unsigned short* dst;
  int j = i;
  if (j < na4) {
    src = a;
    dst = oa;
  } else if ((j -= na4) < nb4) {
    src = b;
    dst = ob;
  } else if ((j -= nb4) < nc4) {
    src = cc;
    dst = oc;
  } else {
    return;
  }
  const float4 v = ((const float4*)src)[j];
  us4 o;
  o[0] = f2bf(v.x);
  o[1] = f2bf(v.y);
  o[2] = f2bf(v.z);
  o[3] = f2bf(v.w);
  ((us4*)dst)[j] = o;
}

// C[M,*] = A[M,K] @ B[N,K]^T + bias (f32), bf16 in, f32 accum.
// MODE 0: scatter Q [bh,tok,hd] (xQSCALE), K [bh,tok,hd], V TRANSPOSED [bh,hd,tok].
// MODE 1: f32 out: outF[row*N+col] = acc + bias.
template <int MODE>
__global__ __launch_bounds__(256) void gemm_bt(
    const bf16* __restrict__ A, const bf16* __restrict__ B,
    const float* __restrict__ bias,
    unsigned short* __restrict__ out0, unsigned short* __restrict__ out1,
    unsigned short* __restrict__ out2, float* __restrict__ outF, int N, int K) {
  __shared__ unsigned short As[128 * 64];
  __shared__ unsigned short Bs[128 * 64];
  const int lane = threadIdx.x & 63;
  const int wv = threadIdx.x >> 6;
  const int m0 = blockIdx.y * 128;
  const int n0 = blockIdx.x * 128;
  const int wr = wv >> 1, wc = wv & 1;

  f32x4 acc[4][4] = {};

  const int srow = lane >> 3;       // 0..7
  const int scol = (lane & 7) * 8;  // element col within K-step
  const bf16* Ag = A + (size_t)(m0 + wv * 32 + srow) * K + scol;
  const bf16* Bg = B + (size_t)(n0 + wv * 32 + srow) * K + scol;

  for (int k0 = 0; k0 < K; k0 += 64) {
#pragma unroll
    for (int i = 0; i < 4; ++i) {
      gload_lds16(Ag + (size_t)(i * 8) * K + k0, As + (wv * 32 + i * 8) * 64);
      gload_lds16(Bg + (size_t)(i * 8) * K + k0, Bs + (wv * 32 + i * 8) * 64);
    }
    __syncthreads();
#pragma unroll
    for (int kk = 0; kk < 2; ++kk) {
      short8 a[4], b[4];
#pragma unroll
      for (int i = 0; i < 4; ++i)
        a[i] = *(const short8*)(As + (wr * 64 + i * 16 + (lane & 15)) * 64 +
                                kk * 32 + (lane >> 4) * 8);
#pragma unroll
      for (int i = 0; i < 4; ++i)
        b[i] = *(const short8*)(Bs + (wc * 64 + i * 16 + (lane & 15)) * 64 +
                                kk * 32 + (lane >> 4) * 8);
#pragma unroll
      for (int mi = 0; mi < 4; ++mi)
#pragma unroll
        for (int ni = 0; ni < 4; ++ni)
          acc[mi][ni] = __builtin_amdgcn_mfma_f32_16x16x32_bf16(
              a[mi], b[ni], acc[mi][ni], 0, 0, 0);
    }
    __syncthreads();
  }

#pragma unroll
  for (int mi = 0; mi < 4; ++mi) {
#pragma unroll
    for (int ni = 0; ni < 4; ++ni) {
      const int col = n0 + wc * 64 + ni * 16 + (lane & 15);
      const float bv = bias[col];
#pragma unroll
      for (int r = 0; r < 4; ++r) {
        const int row = m0 + wr * 64 + mi * 16 + (lane >> 4) * 4 + r;
        float v = acc[mi][ni][r] + bv;
        if (MODE == 0) {
          const int part = col >> 10;
          const int h = (col & 1023) >> 6;
          const int hd = col & 63;
          const int bb = row >> 11;
          const int tok = row & 2047;
          const size_t bh = (size_t)(bb * HEADS + h);
          if (part == 0) {
            out0[(bh * SEQ + tok) * HD + hd] = f2bf(v * QSCALE);
          } else if (part == 1) {
            out1[(bh * SEQ + tok) * HD + hd] = f2bf(v);
          } else {  // V: store transposed [bh][hd][tok]
            out2[(bh * HD + hd) * SEQ + tok] = f2bf(v);
          }
        } else {
          outF[(size_t)row * N + col] = v;
        }
      }
    }
  }
}

// KV-split flash attention. grid (B*H, SEQ/128), 512 thr = 8 waves.
// Waves 0-3: q-subtiles x kv [0,1024). Waves 4-7: same q x kv [1024,2048).
// Flash-merge of the two halves at the end through LDS (P-buffer reused).
// K [bh,kv,hd] / Vt [bh,hd,tok] fragments read straight from global (L2-hot).
// NOTE launch_bounds: hipcc empirically treats the 2nd arg as BLOCKS/CU
// (r5: (512,4) -> 64-VGPR cap -> 726 MB scratch spill). (512,2) caps at
// 128 VGPR under that reading (256 under waves/EU) -> no spill either way.
__global__ __launch_bounds__(512, 2) void attn_kernel(
    const bf16* __restrict__ Q, const bf16* __restrict__ Kx,
    const bf16* __restrict__ Vt, unsigned short* __restrict__ O) {
  __shared__ unsigned short Ps[8][32 * 64];  // per-wave P; reused as f32 o-staging
  __shared__ float Ml[4][32][2];             // partner (m,l) per q-row
  const int lane = threadIdx.x & 63;
  const int wv = threadIdx.x >> 6;  // 0..7
  const int qw = wv & 3;            // q sub-block (32 rows)
  const int half = wv >> 2;         // kv half
  const int c = lane & 15;
  const int q4 = lane >> 4;
  const int bh = blockIdx.x;
  const int b = bh >> 4;
  const int h = bh & 15;
  const int q0 = blockIdx.y * 128 + qw * 32;
  const size_t base = (size_t)bh * SEQ * HD;
  unsigned short* Pw = Ps[wv];

  // Q fragments (pre-scaled by QSCALE in the QKV epilogue)
  short8 qf[2][2];
#pragma unroll
  for (int mi = 0; mi < 2; ++mi)
#pragma unroll
    for (int kk = 0; kk < 2; ++kk)
      qf[mi][kk] = *(const short8*)(Q + base + (size_t)(q0 + mi * 16 + c) * HD +
                                    kk * 32 + q4 * 8);

  f32x4 o[2][4] = {};
  float mrow[2][4], lrow[2][4];
#pragma unroll
  for (int mi = 0; mi < 2; ++mi)
#pragma unroll
    for (int r = 0; r < 4; ++r) {
      mrow[mi][r] = -3.0e38f;
      lrow[mi][r] = 0.f;
    }

  const int kvbase = half * (SEQ / 2);
  for (int t = 0; t < (SEQ / 2) / 64; ++t) {
    const int kv0 = kvbase + t * 64;
    short8 kf[2][4];
#pragma unroll
    for (int kk = 0; kk < 2; ++kk)
#pragma unroll
      for (int n = 0; n < 4; ++n)
        kf[kk][n] = *(const short8*)(Kx + base +
                                     (size_t)(kv0 + n * 16 + c) * HD +
                                     kk * 32 + q4 * 8);

    // S = Q K^T (log2-domain scores)
    f32x4 s[2][4] = {};
    __builtin_amdgcn_s_setprio(1);
#pragma unroll
    for (int kk = 0; kk < 2; ++kk)
#pragma unroll
      for (int n = 0; n < 4; ++n)
#pragma unroll
        for (int mi = 0; mi < 2; ++mi)
          s[mi][n] = __builtin_amdgcn_mfma_f32_16x16x32_bf16(
              qf[mi][kk], kf[kk][n], s[mi][n], 0, 0, 0);
    __builtin_amdgcn_s_setprio(0);

    // V fragments issued here: hide under softmax, live range shorter than kf
    short8 vf[2][4];
#pragma unroll
    for (int kk = 0; kk < 2; ++kk)
#pragma unroll
      for (int n = 0; n < 4; ++n)
        vf[kk][n] = *(const short8*)(Vt + base + (size_t)(n * 16 + c) * SEQ +
                                     kv0 + kk * 32 + q4 * 8);

#pragma unroll
    for (int mi = 0; mi < 2; ++mi) {
      float mx[4];
#pragma unroll
      for (int r = 0; r < 4; ++r) {
        float v = fmaxf(fmaxf(s[mi][0][r], s[mi][1][r]),
                        fmaxf(s[mi][2][r], s[mi][3][r]));
        v = fmaxf(v, __shfl_xor(v, 1));
        v = fmaxf(v, __shfl_xor(v, 2));
        v = fmaxf(v, __shfl_xor(v, 4));
        v = fmaxf(v, __shfl_xor(v, 8));
        mx[r] = v;
      }
      bool lc = true;
#pragma unroll
      for (int r = 0; r < 4; ++r) lc = lc && (mx[r] <= mrow[mi][r] + 8.0f);
      if (!__all(lc)) {  // T13 defer-max (P <= 2^8)
#pragma unroll
        for (int r = 0; r < 4; ++r) {
          const float mnew = fmaxf(mrow[mi][r], mx[r]);
          const float corr = exp2f(mrow[mi][r] - mnew);
          mrow[mi][r] = mnew;
          lrow[mi][r] *= corr;
#pragma unroll
          for (int n = 0; n < 4; ++n) o[mi][n][r] *= corr;
        }
      }
#pragma unroll
      for (int r = 0; r < 4; ++r) {
        const int row = mi * 16 + q4 * 4 + r;
        float rs = 0.f;
#pragma unroll
        for (int n = 0; n < 4; ++n) {
          const float p = exp2f(s[mi][n][r] - mrow[mi][r]);
          rs += p;
          const int col = n * 16 + c;
          Pw[row * 64 + (((col >> 3) ^ (row & 7)) << 3) + (col & 7)] = f2bf(p);
        }
        rs += __shfl_xor(rs, 1);
        rs += __shfl_xor(rs, 2);
        rs += __shfl_xor(rs, 4);
        rs += __shfl_xor(rs, 8);
        lrow[mi][r] += rs;
      }
    }

    // P back as A-fragments (swizzled read), then O += P V
    short8 pa[2][2];
#pragma unroll
    for (int mi = 0; mi < 2; ++mi)
#pragma unroll
      for (int kk = 0; kk < 2; ++kk) {
        const int row = mi * 16 + c;
        const int slot = (kk * 4 + q4) ^ (row & 7);
        pa[mi][kk] = *(const short8*)(Pw + row * 64 + slot * 8);
      }
    __builtin_amdgcn_s_setprio(1);
#pragma unroll
    for (int kk = 0; kk < 2; ++kk)
#pragma unroll
      for (int n = 0; n < 4; ++n)
#pragma unroll
        for (int mi = 0; mi < 2; ++mi)
          o[mi][n] = __builtin_amdgcn_mfma_f32_16x16x32_bf16(
              pa[mi][kk], vf[kk][n], o[mi][n], 0, 0, 0);
    __builtin_amdgcn_s_setprio(0);
  }

  // ---- flash-merge of kv halves (waves 4-7 stage into Ps as f32) ----
  __syncthreads();
  float* Om = (float*)&Ps[0][0];  // 8192 floats = 32 KB; slot qw*2048
  if (half == 1) {
#pragma unroll
    for (int mi = 0; mi < 2; ++mi)
#pragma unroll
      for (int n = 0; n < 4; ++n)
#pragma unroll
        for (int r = 0; r < 4; ++r)
          Om[qw * 2048 + (mi * 16 + q4 * 4 + r) * 64 + n * 16 + c] =
              o[mi][n][r];
    if (c == 0) {
#pragma unroll
      for (int mi = 0; mi < 2; ++mi)
#pragma unroll
        for (int r = 0; r < 4; ++r) {
          Ml[qw][mi * 16 + q4 * 4 + r][0] = mrow[mi][r];
          Ml[qw][mi * 16 + q4 * 4 + r][1] = lrow[mi][r];
        }
    }
  }
  __syncthreads();
  if (half == 0) {
#pragma unroll
    for (int mi = 0; mi < 2; ++mi)
#pragma unroll
      for (int r = 0; r < 4; ++r) {
        const int row = mi * 16 + q4 * 4 + r;
        const float mb = Ml[qw][row][0];
        const float lb = Ml[qw][row][1];
        const float m = fmaxf(mrow[mi][r], mb);
        const float ca = exp2f(mrow[mi][r] - m);
        const float cb = exp2f(mb - m);
        const float inv = 1.0f / (lrow[mi][r] * ca + lb * cb);
#pragma unroll
        for (int n = 0; n < 4; ++n) {
          const float ob = Om[qw * 2048 + row * 64 + n * 16 + c];
          const float res = (o[mi][n][r] * ca + ob * cb) * inv;
          O[((size_t)b * SEQ + q0 + row) * EMB + h * HD + n * 16 + c] =
              f2bf(res);
        }
      }
  }
}

extern "C" void kernel_launch(void* const* d_in, const int* in_sizes, int n_in,
                              void* d_out, int out_size, void* d_ws,
                              size_t ws_size, hipStream_t stream) {
  const float* x = (const float*)d_in[0];
  const float* qkv_w = (const float*)d_in[1];
  const float* qkv_b = (const float*)d_in[2];
  const float* proj_w = (const float*)d_in[3];
  const float* proj_b = (const float*)d_in[4];

  const size_t n_x = (size_t)ROWS * EMB;
  const size_t n_qkvw = (size_t)3 * EMB * EMB;
  const size_t n_projw = (size_t)EMB * EMB;
  const size_t elems = (size_t)BATCH * HEADS * SEQ * HD;

  unsigned short* xb = (unsigned short*)d_ws;
  unsigned short* wqkv = xb + n_x;
  unsigned short* wproj = wqkv + n_qkvw;
  unsigned short* Qw = wproj + n_projw;
  unsigned short* Kw = Qw + elems;
  unsigned short* Vw = Kw + elems;  // transposed [bh][hd][tok]
  unsigned short* Ow = Vw + elems;  // [B, SEQ, EMB]

  // 0) f32 -> bf16 conversions (single fused launch)
  const int na4 = (int)(n_x / 4), nb4 = (int)(n_qkvw / 4),
            nc4 = (int)(n_projw / 4);
  cvt3_kernel<<<(na4 + nb4 + nc4 + 255) / 256, 256, 0, stream>>>(
      x, qkv_w, proj_w, xb, wqkv, wproj, na4, nb4, nc4);

  // 1) QKV projection -> Q/K scatter + V transposed scatter
  dim3 g1(3 * EMB / 128, ROWS / 128);  // 24 x 32
  gemm_bt<0><<<g1, 256, 0, stream>>>((const bf16*)xb, (const bf16*)wqkv, qkv_b,
                                     Qw, Kw, Vw, nullptr, 3 * EMB, EMB);

  // 2) KV-split flash attention -> Ow [B, SEQ, EMB]
  dim3 g2(BATCH * HEADS, SEQ / 128);  // 32 x 16, 512 thr
  attn_kernel<<<g2, 512, 0, stream>>>((const bf16*)Qw, (const bf16*)Kw,
                                      (const bf16*)Vw, Ow);

  // 3) output projection + bias -> d_out (f32)
  dim3 g3(EMB / 128, ROWS / 128);  // 8 x 32
  gemm_bt<1><<<g3, 256, 0, stream>>>((const bf16*)Ow, (const bf16*)wproj,
                                     proj_b, nullptr, nullptr, nullptr,
                                     (float*)d_out, EMB, EMB);
}

// Round 7
// 221.910 us; speedup vs baseline: 2.0089x; 1.0227x over previous
//
#include <hip/hip_runtime.h>
#include <hip/hip_bf16.h>

typedef __hip_bfloat16 bf16;
typedef __attribute__((ext_vector_type(8))) short short8;
typedef __attribute__((ext_vector_type(4))) float f32x4;
typedef __attribute__((ext_vector_type(4))) unsigned short us4;
typedef __attribute__((ext_vector_type(4))) unsigned int u32x4;

#define EMB 1024
#define HEADS 16
#define HD 64
#define BATCH 2
#define SEQ 2048
#define ROWS (BATCH * SEQ) /* 4096 */

// Q pre-scale: attention 1/sqrt(64) folded with log2(e): softmax in exp2 domain.
#define QSCALE (0.125f * 1.44269504088896340736f)

__device__ __forceinline__ void gload_lds16(const void* g, void* l) {
  __builtin_amdgcn_global_load_lds(
      (const __attribute__((address_space(1))) void*)g,
      (__attribute__((address_space(3))) void*)l, 16, 0, 0);
}

__device__ __forceinline__ unsigned short f2bf(float x) {
  bf16 h = __float2bfloat16(x);
  return __builtin_bit_cast(unsigned short, h);
}

// packed f32x2 -> bf16x2 (lo = src0, hi = src1), single HW instruction
__device__ __forceinline__ unsigned int cvtpk(float lo, float hi) {
  unsigned int r;
  asm("v_cvt_pk_bf16_f32 %0, %1, %2" : "=v"(r) : "v"(lo), "v"(hi));
  return r;
}

// fused f32 -> bf16 (RN) for x, qkv_w, proj_w (3 segments, one launch).
__global__ __launch_bounds__(256) void cvt3_kernel(
    const float* __restrict__ a, const float* __restrict__ b,
    const float* __restrict__ cc, unsigned short* __restrict__ oa,
    unsigned short* __restrict__ ob, unsigned short* __restrict__ oc, int na4,
    int nb4, int nc4) {
  int i = blockIdx.x * 256 + threadIdx.x;
  const float* src;
  unsigned short* dst;
  int j = i;
  if (j < na4) {
    src = a;
    dst = oa;
  } else if ((j -= na4) < nb4) {
    src = b;
    dst = ob;
  } else if ((j -= nb4) < nc4) {
    src = cc;
    dst = oc;
  } else {
    return;
  }
  const float4 v = ((const float4*)src)[j];
  us4 o;
  o[0] = f2bf(v.x);
  o[1] = f2bf(v.y);
  o[2] = f2bf(v.z);
  o[3] = f2bf(v.w);
  ((us4*)dst)[j] = o;
}

// C[M,*] = A[M,K] @ B[N,K]^T + bias (f32), bf16 in, f32 accum.
// MODE 0: scatter Q [bh,tok,hd] (xQSCALE), K [bh,tok,hd], V TRANSPOSED [bh,hd,tok].
// MODE 1: f32 out: outF[row*N+col] = acc + bias.
template <int MODE>
__global__ __launch_bounds__(256) void gemm_bt(
    const bf16* __restrict__ A, const bf16* __restrict__ B,
    const float* __restrict__ bias,
    unsigned short* __restrict__ out0, unsigned short* __restrict__ out1,
    unsigned short* __restrict__ out2, float* __restrict__ outF, int N, int K) {
  __shared__ unsigned short As[128 * 64];
  __shared__ unsigned short Bs[128 * 64];
  const int lane = threadIdx.x & 63;
  const int wv = threadIdx.x >> 6;
  const int m0 = blockIdx.y * 128;
  const int n0 = blockIdx.x * 128;
  const int wr = wv >> 1, wc = wv & 1;

  f32x4 acc[4][4] = {};

  const int srow = lane >> 3;
  const int scol = (lane & 7) * 8;
  const bf16* Ag = A + (size_t)(m0 + wv * 32 + srow) * K + scol;
  const bf16* Bg = B + (size_t)(n0 + wv * 32 + srow) * K + scol;

  for (int k0 = 0; k0 < K; k0 += 64) {
#pragma unroll
    for (int i = 0; i < 4; ++i) {
      gload_lds16(Ag + (size_t)(i * 8) * K + k0, As + (wv * 32 + i * 8) * 64);
      gload_lds16(Bg + (size_t)(i * 8) * K + k0, Bs + (wv * 32 + i * 8) * 64);
    }
    __syncthreads();
#pragma unroll
    for (int kk = 0; kk < 2; ++kk) {
      short8 a[4], b[4];
#pragma unroll
      for (int i = 0; i < 4; ++i)
        a[i] = *(const short8*)(As + (wr * 64 + i * 16 + (lane & 15)) * 64 +
                                kk * 32 + (lane >> 4) * 8);
#pragma unroll
      for (int i = 0; i < 4; ++i)
        b[i] = *(const short8*)(Bs + (wc * 64 + i * 16 + (lane & 15)) * 64 +
                                kk * 32 + (lane >> 4) * 8);
#pragma unroll
      for (int mi = 0; mi < 4; ++mi)
#pragma unroll
        for (int ni = 0; ni < 4; ++ni)
          acc[mi][ni] = __builtin_amdgcn_mfma_f32_16x16x32_bf16(
              a[mi], b[ni], acc[mi][ni], 0, 0, 0);
    }
    __syncthreads();
  }

#pragma unroll
  for (int mi = 0; mi < 4; ++mi) {
#pragma unroll
    for (int ni = 0; ni < 4; ++ni) {
      const int col = n0 + wc * 64 + ni * 16 + (lane & 15);
      const float bv = bias[col];
#pragma unroll
      for (int r = 0; r < 4; ++r) {
        const int row = m0 + wr * 64 + mi * 16 + (lane >> 4) * 4 + r;
        float v = acc[mi][ni][r] + bv;
        if (MODE == 0) {
          const int part = col >> 10;
          const int h = (col & 1023) >> 6;
          const int hd = col & 63;
          const int bb = row >> 11;
          const int tok = row & 2047;
          const size_t bh = (size_t)(bb * HEADS + h);
          if (part == 0) {
            out0[(bh * SEQ + tok) * HD + hd] = f2bf(v * QSCALE);
          } else if (part == 1) {
            out1[(bh * SEQ + tok) * HD + hd] = f2bf(v);
          } else {  // V: store transposed [bh][hd][tok]
            out2[(bh * HD + hd) * SEQ + tok] = f2bf(v);
          }
        } else {
          outF[(size_t)row * N + col] = v;
        }
      }
    }
  }
}

// Swapped-operand flash attention, softmax fully in-register (T12).
// grid (B*H, SEQ/64-q-rows-per-block... 32), 256 thr = 4 waves:
//   wave = (half = wv>>1) x (qw = wv&1). Each wave: 32 q-rows, half the KV.
// S^T = mfma(K, Q): lane (c,g) owns S[q0+c][kv: n*16+g*4+r] -> row ops local.
// P^T B-fragments for O^T = mfma(V^T, P^T) built via 16x ds_bpermute.
// Flash-merge of halves via LDS at the end.
__global__ __launch_bounds__(256, 2) void attn_kernel(
    const bf16* __restrict__ Q, const bf16* __restrict__ Kx,
    const bf16* __restrict__ Vt, unsigned short* __restrict__ O) {
  __shared__ float Om[2][32][68];  // [qw][row][d] padded
  __shared__ float Ml[2][32][2];
  const int lane = threadIdx.x & 63;
  const int wv = threadIdx.x >> 6;  // 0..3
  const int qw = wv & 1;
  const int half = wv >> 1;
  const int c = lane & 15;   // q-row within 16-block
  const int q4 = lane >> 4;  // lane group g
  const int bh = blockIdx.x;
  const int b = bh >> 4;
  const int h = bh & 15;
  const int q0 = blockIdx.y * 64 + qw * 32;
  const size_t base = (size_t)bh * SEQ * HD;

  // bpermute source-lane indices (byte addressed): src = (2*(g&1)+h)*16 + c
  const int idx0 = (((q4 & 1) << 5) | c) << 2;
  const int idx1 = idx0 + 64;
  const bool hiSel = q4 >= 2;

  // Q fragments as MFMA *B* operand: B[col=lane&15 -> q][k = kk*32+q4*8]
  short8 qf[2][2];
#pragma unroll
  for (int blk = 0; blk < 2; ++blk)
#pragma unroll
    for (int kk = 0; kk < 2; ++kk)
      qf[blk][kk] = *(const short8*)(Q + base +
                                     (size_t)(q0 + blk * 16 + c) * HD +
                                     kk * 32 + q4 * 8);

  f32x4 oT[2][4] = {};  // O^T: lane (c,g): O[q0+blk*16+c][d = nd*16+g*4+r]
  float m[2], l[2];
#pragma unroll
  for (int blk = 0; blk < 2; ++blk) {
    m[blk] = -3.0e38f;
    l[blk] = 0.f;
  }

  const int kvbase = half * (SEQ / 2);
  for (int t = 0; t < (SEQ / 2) / 64; ++t) {
    const int kv0 = kvbase + t * 64;
    // K fragments as MFMA *A* operand: A[row=lane&15 -> kv][k=d]
    short8 kf[2][4];
#pragma unroll
    for (int kk = 0; kk < 2; ++kk)
#pragma unroll
      for (int n = 0; n < 4; ++n)
        kf[kk][n] = *(const short8*)(Kx + base +
                                     (size_t)(kv0 + n * 16 + c) * HD +
                                     kk * 32 + q4 * 8);

    // S^T = K Q^T : sT[blk][n] at lane = S[q0+blk*16+c][kv0+n*16+q4*4+r]
    f32x4 sT[2][4] = {};
    __builtin_amdgcn_s_setprio(1);
#pragma unroll
    for (int kk = 0; kk < 2; ++kk)
#pragma unroll
      for (int n = 0; n < 4; ++n)
#pragma unroll
        for (int blk = 0; blk < 2; ++blk)
          sT[blk][n] = __builtin_amdgcn_mfma_f32_16x16x32_bf16(
              kf[kk][n], qf[blk][kk], sT[blk][n], 0, 0, 0);
    __builtin_amdgcn_s_setprio(0);

    // V^T fragments as MFMA *A* operand: A[row=lane&15 -> d][k=kv]
    short8 vf[2][4];
#pragma unroll
    for (int kk = 0; kk < 2; ++kk)
#pragma unroll
      for (int n = 0; n < 4; ++n)
        vf[kk][n] = *(const short8*)(Vt + base + (size_t)(n * 16 + c) * SEQ +
                                     kv0 + kk * 32 + q4 * 8);

#pragma unroll
    for (int blk = 0; blk < 2; ++blk) {
      // row max: 15 in-reg + xor16 + xor32 (all 4 dup-lanes converge)
      float mx = sT[blk][0][0];
#pragma unroll
      for (int n = 0; n < 4; ++n)
#pragma unroll
        for (int r = 0; r < 4; ++r) mx = fmaxf(mx, sT[blk][n][r]);
      mx = fmaxf(mx, __shfl_xor(mx, 16));
      mx = fmaxf(mx, __shfl_xor(mx, 32));

      if (!__all(mx <= m[blk] + 8.0f)) {  // T13 defer-max (P <= 2^8)
        const float mnew = fmaxf(m[blk], mx);
        const float corr = exp2f(m[blk] - mnew);
        m[blk] = mnew;
        l[blk] *= corr;
#pragma unroll
        for (int nd = 0; nd < 4; ++nd)
#pragma unroll
          for (int r = 0; r < 4; ++r) oT[blk][nd][r] *= corr;
      }

      // P = exp2(S - m), packed to bf16x2 words in-register
      unsigned int W[4][2];
      float rs = 0.f;
#pragma unroll
      for (int n = 0; n < 4; ++n) {
        const float p0 = exp2f(sT[blk][n][0] - m[blk]);
        const float p1 = exp2f(sT[blk][n][1] - m[blk]);
        const float p2 = exp2f(sT[blk][n][2] - m[blk]);
        const float p3 = exp2f(sT[blk][n][3] - m[blk]);
        rs += (p0 + p1) + (p2 + p3);
        W[n][0] = cvtpk(p0, p1);
        W[n][1] = cvtpk(p2, p3);
      }
      rs += __shfl_xor(rs, 16);
      rs += __shfl_xor(rs, 32);
      l[blk] += rs;

      // redistribute P^T into B-operand layout:
      // target word (kk,w) <- src lane (c, 2*(g&1)+(w>>1)), word [2kk+(g>>1)][w&1]
      unsigned int T[2][4];
#pragma unroll
      for (int w = 0; w < 4; ++w) {
        const int idx = (w >> 1) ? idx1 : idx0;
        const int rp = w & 1;
        const int b0 = __builtin_amdgcn_ds_bpermute(idx, (int)W[0][rp]);
        const int b1 = __builtin_amdgcn_ds_bpermute(idx, (int)W[1][rp]);
        const int b2 = __builtin_amdgcn_ds_bpermute(idx, (int)W[2][rp]);
        const int b3 = __builtin_amdgcn_ds_bpermute(idx, (int)W[3][rp]);
        T[0][w] = (unsigned int)(hiSel ? b1 : b0);
        T[1][w] = (unsigned int)(hiSel ? b3 : b2);
      }

      // O^T += V^T P^T
      __builtin_amdgcn_s_setprio(1);
#pragma unroll
      for (int kk = 0; kk < 2; ++kk) {
        u32x4 tw;
        tw[0] = T[kk][0];
        tw[1] = T[kk][1];
        tw[2] = T[kk][2];
        tw[3] = T[kk][3];
        const short8 pb = __builtin_bit_cast(short8, tw);
#pragma unroll
        for (int nd = 0; nd < 4; ++nd)
          oT[blk][nd] = __builtin_amdgcn_mfma_f32_16x16x32_bf16(
              vf[kk][nd], pb, oT[blk][nd], 0, 0, 0);
      }
      __builtin_amdgcn_s_setprio(0);
    }
  }

  // ---- flash-merge of kv halves ----
  __syncthreads();
  if (half == 1) {
#pragma unroll
    for (int blk = 0; blk < 2; ++blk) {
      const int row = blk * 16 + c;
#pragma unroll
      for (int nd = 0; nd < 4; ++nd) {
        float4 st;
        st.x = oT[blk][nd][0];
        st.y = oT[blk][nd][1];
        st.z = oT[blk][nd][2];
        st.w = oT[blk][nd][3];
        *(float4*)&Om[qw][row][nd * 16 + q4 * 4] = st;
      }
      if (q4 == 0) {
        Ml[qw][row][0] = m[blk];
        Ml[qw][row][1] = l[blk];
      }
    }
  }
  __syncthreads();
  if (half == 0) {
#pragma unroll
    for (int blk = 0; blk < 2; ++blk) {
      const int row = blk * 16 + c;
      const float mb = Ml[qw][row][0];
      const float lb = Ml[qw][row][1];
      const float mm = fmaxf(m[blk], mb);
      const float ca = exp2f(m[blk] - mm);
      const float cb = exp2f(mb - mm);
      const float inv = 1.0f / (l[blk] * ca + lb * cb);
#pragma unroll
      for (int nd = 0; nd < 4; ++nd) {
        const float4 ob = *(const float4*)&Om[qw][row][nd * 16 + q4 * 4];
        us4 ov;
        ov[0] = f2bf((oT[blk][nd][0] * ca + ob.x * cb) * inv);
        ov[1] = f2bf((oT[blk][nd][1] * ca + ob.y * cb) * inv);
        ov[2] = f2bf((oT[blk][nd][2] * ca + ob.z * cb) * inv);
        ov[3] = f2bf((oT[blk][nd][3] * ca + ob.w * cb) * inv);
        *(us4*)&O[((size_t)b * SEQ + q0 + row) * EMB + h * HD + nd * 16 +
                  q4 * 4] = ov;
      }
    }
  }
}

extern "C" void kernel_launch(void* const* d_in, const int* in_sizes, int n_in,
                              void* d_out, int out_size, void* d_ws,
                              size_t ws_size, hipStream_t stream) {
  const float* x = (const float*)d_in[0];
  const float* qkv_w = (const float*)d_in[1];
  const float* qkv_b = (const float*)d_in[2];
  const float* proj_w = (const float*)d_in[3];
  const float* proj_b = (const float*)d_in[4];

  const size_t n_x = (size_t)ROWS * EMB;
  const size_t n_qkvw = (size_t)3 * EMB * EMB;
  const size_t n_projw = (size_t)EMB * EMB;
  const size_t elems = (size_t)BATCH * HEADS * SEQ * HD;

  unsigned short* xb = (unsigned short*)d_ws;
  unsigned short* wqkv = xb + n_x;
  unsigned short* wproj = wqkv + n_qkvw;
  unsigned short* Qw = wproj + n_projw;
  unsigned short* Kw = Qw + elems;
  unsigned short* Vw = Kw + elems;  // transposed [bh][hd][tok]
  unsigned short* Ow = Vw + elems;  // [B, SEQ, EMB]

  // 0) f32 -> bf16 conversions (single fused launch)
  const int na4 = (int)(n_x / 4), nb4 = (int)(n_qkvw / 4),
            nc4 = (int)(n_projw / 4);
  cvt3_kernel<<<(na4 + nb4 + nc4 + 255) / 256, 256, 0, stream>>>(
      x, qkv_w, proj_w, xb, wqkv, wproj, na4, nb4, nc4);

  // 1) QKV projection -> Q/K scatter + V transposed scatter
  dim3 g1(3 * EMB / 128, ROWS / 128);  // 24 x 32
  gemm_bt<0><<<g1, 256, 0, stream>>>((const bf16*)xb, (const bf16*)wqkv, qkv_b,
                                     Qw, Kw, Vw, nullptr, 3 * EMB, EMB);

  // 2) swapped-operand flash attention -> Ow [B, SEQ, EMB]
  dim3 g2(BATCH * HEADS, SEQ / 64);  // 32 x 32, 256 thr
  attn_kernel<<<g2, 256, 0, stream>>>((const bf16*)Qw, (const bf16*)Kw,
                                      (const bf16*)Vw, Ow);

  // 3) output projection + bias -> d_out (f32)
  dim3 g3(EMB / 128, ROWS / 128);  // 8 x 32
  gemm_bt<1><<<g3, 256, 0, stream>>>((const bf16*)Ow, (const bf16*)wproj,
                                     proj_b, nullptr, nullptr, nullptr,
                                     (float*)d_out, EMB, EMB);
}